// Round 1
// 546.627 us; speedup vs baseline: 1.0908x; 1.0908x over previous
//
#include <hip/hip_runtime.h>
#include <hip/hip_bf16.h>
#include <stdint.h>

// Problem constants
//   x:[32,2048,512] fp32  W*:[512,512] fp32  b*:[512] fp32  factor:[1,64,256,8] fp32
//   Output fp32 [32,2048,512].
//   Internally: cast x,W to bf16; q/k/v proj via bf16 MFMA; Q/K/V staged bf16.
//   per (b,a): slice = rows [b*2048+a*32, +32) x 512 of Q/K/V
//     Layout note: within a slice, element (h, lr) lives at byte (h*256+lr)*2
//     — i.e. the slice IS a contiguous row-major [64 h][256 lr] bf16 matrix.

typedef unsigned short ushort_t;

using bf16x8 = __attribute__((ext_vector_type(8))) short;   // 8 bf16 (4 VGPRs)
using f32x4  = __attribute__((ext_vector_type(4))) float;   // MFMA acc

__device__ __forceinline__ float bf2f(unsigned short u) {
  union { unsigned int i; float f; } v;
  v.i = ((unsigned int)u) << 16;
  return v.f;
}
__device__ __forceinline__ unsigned short f2bf(float f) {
  __hip_bfloat16 h = __float2bfloat16(f);  // round-to-nearest-even
  return *reinterpret_cast<unsigned short*>(&h);
}

// async global->LDS, 16B per lane. LDS dest = wave-uniform base + lane*16.
__device__ __forceinline__ void load_lds16(const void* g, void* l) {
  __builtin_amdgcn_global_load_lds(
      (const __attribute__((address_space(1))) unsigned int*)g,
      (__attribute__((address_space(3))) unsigned int*)l,
      16, 0, 0);
}

// ---------------------------------------------------------------------------
// Kernel 0: fp32 -> bf16 cast, 4 elems/thread.
// ---------------------------------------------------------------------------
__global__ __launch_bounds__(256)
void cast_f32_bf16(const float* __restrict__ src, ushort_t* __restrict__ dst,
                   int n4) {
  int i = blockIdx.x * blockDim.x + threadIdx.x;
  if (i < n4) {
    float4 v = ((const float4*)src)[i];
    ushort_t p[4] = {f2bf(v.x), f2bf(v.y), f2bf(v.z), f2bf(v.w)};
    *(uint2*)(dst + 4 * (size_t)i) = *(const uint2*)p;
  }
}

// ---------------------------------------------------------------------------
// Kernel 1: C[M=65536, N=512] = X[M,512] @ W[N,512]^T + bias, bf16 MFMA.
// grid = (N/128, M/128, 3); block = 256 (4 waves). BK=32, m97 2-barrier loop.
// (unchanged this round — attn_bc is the measured top dispatch)
// ---------------------------------------------------------------------------
__global__ __launch_bounds__(256)
void gemm_qkv(const ushort_t* __restrict__ X,
              const ushort_t* __restrict__ W0, const float* __restrict__ B0,
              const ushort_t* __restrict__ W1, const float* __restrict__ B1,
              const ushort_t* __restrict__ W2, const float* __restrict__ B2,
              ushort_t* __restrict__ Qo, ushort_t* __restrict__ Ko,
              ushort_t* __restrict__ Vo) {
  __shared__ __align__(16) short sA[128 * 32];  // [row][k] row-major, no pad
  __shared__ __align__(16) short sB[128 * 32];

  const ushort_t* W;
  const float* Bi;
  ushort_t* O;
  if (blockIdx.z == 0)      { W = W0; Bi = B0; O = Qo; }
  else if (blockIdx.z == 1) { W = W1; Bi = B1; O = Ko; }
  else                      { W = W2; Bi = B2; O = Vo; }

  const int tid  = threadIdx.x;
  const int lane = tid & 63;
  const int wid  = tid >> 6;
  const int m0 = blockIdx.y * 128;
  const int n0 = blockIdx.x * 128;
  const int wave_m = (wid & 1) * 64;
  const int wave_n = (wid >> 1) * 64;
  const int quad = lane >> 4;
  const int l15  = lane & 15;

  f32x4 acc[4][4];
#pragma unroll
  for (int i = 0; i < 4; ++i)
#pragma unroll
    for (int j = 0; j < 4; ++j) acc[i][j] = f32x4{0.f, 0.f, 0.f, 0.f};

  // staging segments: 512 segs of 16B per tile; wave w covers [w*128, +128)
  const int s0 = wid * 128 + lane;
  const int s1 = s0 + 64;
  short* ldsA0 = &sA[(wid * 128) * 8];
  short* ldsA1 = &sA[(wid * 128 + 64) * 8];
  short* ldsB0 = &sB[(wid * 128) * 8];
  short* ldsB1 = &sB[(wid * 128 + 64) * 8];

  for (int kt = 0; kt < 512; kt += 32) {
    const ushort_t* ga0 = X + ((size_t)(m0 + (s0 >> 2)) << 9) + kt + (s0 & 3) * 8;
    const ushort_t* ga1 = X + ((size_t)(m0 + (s1 >> 2)) << 9) + kt + (s1 & 3) * 8;
    const ushort_t* gb0 = W + ((size_t)(n0 + (s0 >> 2)) << 9) + kt + (s0 & 3) * 8;
    const ushort_t* gb1 = W + ((size_t)(n0 + (s1 >> 2)) << 9) + kt + (s1 & 3) * 8;
    load_lds16(ga0, ldsA0);
    load_lds16(ga1, ldsA1);
    load_lds16(gb0, ldsB0);
    load_lds16(gb1, ldsB1);
    __syncthreads();  // drains vmcnt(0) -> LDS tiles valid

    bf16x8 af[4], bfr[4];
#pragma unroll
    for (int i = 0; i < 4; ++i)
      af[i] = *(const bf16x8*)&sA[(wave_m + i * 16 + l15) * 32 + quad * 8];
#pragma unroll
    for (int j = 0; j < 4; ++j)
      bfr[j] = *(const bf16x8*)&sB[(wave_n + j * 16 + l15) * 32 + quad * 8];
#pragma unroll
    for (int i = 0; i < 4; ++i)
#pragma unroll
      for (int j = 0; j < 4; ++j)
        acc[i][j] = __builtin_amdgcn_mfma_f32_16x16x32_bf16(af[i], bfr[j],
                                                            acc[i][j], 0, 0, 0);
    __syncthreads();  // all waves done reading before next stage overwrites
  }

  // epilogue: C/D layout col=lane&15, row=(lane>>4)*4+reg  [verified m89/m91]
#pragma unroll
  for (int j = 0; j < 4; ++j) {
    const int gn = n0 + wave_n + j * 16 + l15;
    const float bv = Bi[gn];
#pragma unroll
    for (int i = 0; i < 4; ++i) {
      const int gmBase = m0 + wave_m + i * 16 + quad * 4;
      f32x4 c = acc[i][j];
#pragma unroll
      for (int rg = 0; rg < 4; ++rg) {
        O[((size_t)(gmBase + rg) << 9) + gn] = f2bf(c[rg] + bv);
      }
    }
  }
}

// ---------------------------------------------------------------------------
// Kernel 2 (v3): per (b,a) block. grid = (64, 32); block = 256.
// Phase 1: k2/v2 factor contraction. K/V loads HOISTED back-to-back so the 8
//          16B accesses per 128B line are adjacent instructions (MSHR-merged
//          -> one HBM line fetch; no reliance on L2 residency across the FMA
//          block). v2 stored transposed for vectorized PV reads.
// Phase 2a: thread=lr computes scores+softmax (Q column reads: 128B/wave,
//           each line consumed in one instruction — already fetch-efficient).
//           Probs go to LDS.
// Phase 2b: remapped so stores are wave-contiguous (64 lanes x 16B = 1KB/instr,
//           full lines -> no read-for-ownership fetch of the output).
// ---------------------------------------------------------------------------
__global__ __launch_bounds__(256, 4)
void attn_bc(const ushort_t* __restrict__ Q, const ushort_t* __restrict__ K,
             const ushort_t* __restrict__ V, const float* __restrict__ F,
             float* __restrict__ Out) {
  const int a = blockIdx.x;  // 0..63
  const int b = blockIdx.y;  // 0..31
  const int t = threadIdx.x; // 0..255

  __shared__ float k2[64][8];    // [h][r]   2 KB (phase-2a reads broadcast)
  __shared__ float v2T[8][64];   // [r][h]   2 KB (phase-2b reads float4 on h)
  __shared__ float pl[256][8];   // [lr][r]  8 KB softmax probs

  // ---- Phase 1: k2[h][r] = sum_lr K[h][lr] * f[lr][r]; same for v2 --------
  {
    const int h = t >> 2;   // 0..63
    const int c = t & 3;    // lr-chunk of 64
    const size_t sliceoff = ((size_t)(b * 2048 + a * 32) << 9);
    const ushort_t* Kp = K + sliceoff + (size_t)h * 256 + c * 64;
    const ushort_t* Vp = V + sliceoff + (size_t)h * 256 + c * 64;
    const float* Fp = F + (size_t)a * 2048 + (size_t)(c * 64) * 8;

    // Hoist the full 128B-per-thread K and V reads: 8+8 back-to-back uint4
    // loads. Adjacent instructions hitting the same cache line merge in the
    // miss queue -> each K/V line fetched from HBM exactly once.
    uint4 kr[8], vr[8];
#pragma unroll
    for (int u = 0; u < 8; ++u) kr[u] = *(const uint4*)(Kp + u * 8);
#pragma unroll
    for (int u = 0; u < 8; ++u) vr[u] = *(const uint4*)(Vp + u * 8);

    float accK[8], accV[8];
#pragma unroll
    for (int r = 0; r < 8; ++r) { accK[r] = 0.f; accV[r] = 0.f; }

#pragma unroll
    for (int u = 0; u < 8; ++u) {
      const unsigned short* ks = (const unsigned short*)&kr[u];
      const unsigned short* vs = (const unsigned short*)&vr[u];
#pragma unroll
      for (int j = 0; j < 8; ++j) {
        const float kv = bf2f(ks[j]);
        const float vv = bf2f(vs[j]);
        float fr[8];
        *(float4*)&fr[0] = *(const float4*)(Fp + (size_t)(u * 8 + j) * 8);
        *(float4*)&fr[4] = *(const float4*)(Fp + (size_t)(u * 8 + j) * 8 + 4);
#pragma unroll
        for (int r = 0; r < 8; ++r) {
          accK[r] += kv * fr[r];
          accV[r] += vv * fr[r];
        }
      }
    }
    // reduce across the 4 chunk-lanes (t^1, t^2 within same wave)
#pragma unroll
    for (int r = 0; r < 8; ++r) {
      accK[r] += __shfl_xor(accK[r], 1);
      accK[r] += __shfl_xor(accK[r], 2);
      accV[r] += __shfl_xor(accV[r], 1);
      accV[r] += __shfl_xor(accV[r], 2);
    }
    if (c == 0) {
#pragma unroll
      for (int r = 0; r < 8; ++r) {
        k2[h][r] = accK[r];
        v2T[r][h] = accV[r];   // transposed store for phase 2b
      }
    }
  }
  __syncthreads();

  // ---- Phase 2a: thread t = lr; scores, softmax, probs -> LDS -------------
  {
    const int lr = t;
    float s[8];
#pragma unroll
    for (int r = 0; r < 8; ++r) s[r] = 0.f;

    const ushort_t* Qp = Q + (((size_t)(b * 2048 + a * 32)) << 9) + lr;
#pragma unroll 16
    for (int h = 0; h < 64; ++h) {
      const float qv = bf2f(Qp[(size_t)h * 256]);   // column read, 128B/wave
      float4 ka = *(const float4*)&k2[h][0];        // broadcast
      float4 kb = *(const float4*)&k2[h][4];
      s[0] += qv * ka.x; s[1] += qv * ka.y; s[2] += qv * ka.z; s[3] += qv * ka.w;
      s[4] += qv * kb.x; s[5] += qv * kb.y; s[6] += qv * kb.z; s[7] += qv * kb.w;
    }

    // scale by 1/sqrt(64), softmax over r (8)
    float mx = -1e30f;
#pragma unroll
    for (int r = 0; r < 8; ++r) { s[r] *= 0.125f; mx = fmaxf(mx, s[r]); }
    float sum = 0.f;
#pragma unroll
    for (int r = 0; r < 8; ++r) { s[r] = __expf(s[r] - mx); sum += s[r]; }
    const float inv = 1.0f / sum;
    *(float4*)&pl[lr][0] = float4{s[0] * inv, s[1] * inv, s[2] * inv, s[3] * inv};
    *(float4*)&pl[lr][4] = float4{s[4] * inv, s[5] * inv, s[6] * inv, s[7] * inv};
  }
  __syncthreads();

  // ---- Phase 2b: coalesced PV + store -------------------------------------
  // thread t owns out cols [g*64 + h0, +4) -> block writes 4KB contiguous per
  // iteration (16B/lane, full lines).  out[row][g*64+h] = sum_r p[row*8+g][r]*v2[h][r]
  {
    float* Ob = Out + (((size_t)(b * 2048 + a * 32)) << 9);
    const int g  = (t >> 4) & 7;
    const int h0 = (t & 15) * 4;
#pragma unroll
    for (int iter = 0; iter < 16; ++iter) {
      const int row = (t >> 7) + iter * 2;
      const int lr = row * 8 + g;
      float p[8];
      *(float4*)&p[0] = *(const float4*)&pl[lr][0];   // broadcast within 16 lanes
      *(float4*)&p[4] = *(const float4*)&pl[lr][4];
      float4 o = float4{0.f, 0.f, 0.f, 0.f};
#pragma unroll
      for (int r = 0; r < 8; ++r) {
        float4 vt = *(const float4*)&v2T[r][h0];      // 2-way bank alias = free
        o.x += p[r] * vt.x; o.y += p[r] * vt.y;
        o.z += p[r] * vt.z; o.w += p[r] * vt.w;
      }
      *(float4*)(Ob + (size_t)row * 512 + g * 64 + h0) = o;
    }
  }
}

// ---------------------------------------------------------------------------
extern "C" void kernel_launch(void* const* d_in, const int* in_sizes, int n_in,
                              void* d_out, int out_size, void* d_ws,
                              size_t ws_size, hipStream_t stream) {
  const float* x  = (const float*)d_in[0];
  const float* Wq = (const float*)d_in[1];
  const float* bq = (const float*)d_in[2];
  const float* Wk = (const float*)d_in[3];
  const float* bk = (const float*)d_in[4];
  const float* Wv = (const float*)d_in[5];
  const float* bv = (const float*)d_in[6];
  const float* f  = (const float*)d_in[7];
  float* out = (float*)d_out;

  // ws layout (bf16 shorts):
  //   xb:  65536*512            = 33,554,432   (67 MB)
  //   wb:  3 * 512*512          =    786,432   (1.5 MB)
  //   Qb/Kb/Vb: 3 * 33,554,432               (201 MB)
  ushort_t* xb = (ushort_t*)d_ws;
  ushort_t* wb = xb + 33554432u;
  ushort_t* Qb = wb + 786432u;
  ushort_t* Kb = Qb + 33554432u;
  ushort_t* Vb = Kb + 33554432u;

  cast_f32_bf16<<<33554432 / 4 / 256, 256, 0, stream>>>(x, xb, 33554432 / 4);
  cast_f32_bf16<<<262144 / 4 / 256, 256, 0, stream>>>(Wq, wb, 262144 / 4);
  cast_f32_bf16<<<262144 / 4 / 256, 256, 0, stream>>>(Wk, wb + 262144u, 262144 / 4);
  cast_f32_bf16<<<262144 / 4 / 256, 256, 0, stream>>>(Wv, wb + 524288u, 262144 / 4);

  dim3 g1(4, 512, 3);  // N-blocks, M-blocks, {q,k,v}
  gemm_qkv<<<g1, 256, 0, stream>>>(xb, wb, bq, wb + 262144u, bk,
                                   wb + 524288u, bv, Qb, Kb, Vb);

  dim3 g2(64, 32);  // (a, b)
  attn_bc<<<g2, 256, 0, stream>>>(Qb, Kb, Vb, f, out);
}

// Round 2
// 469.741 us; speedup vs baseline: 1.2693x; 1.1637x over previous
//
#include <hip/hip_runtime.h>
#include <hip/hip_bf16.h>
#include <stdint.h>

// Problem constants
//   x:[32,2048,512] fp32  W*:[512,512] fp32  b*:[512] fp32  factor:[1,64,256,8] fp32
//   Output fp32 [32,2048,512].
//   Internally: cast x,W to bf16; q/k/v proj via bf16 MFMA; Q/K/V staged bf16.
//   per (b,a): slice = rows [b*2048+a*32, +32) x 512 of Q/K/V
//     slice IS a contiguous row-major [64 h][256 lr] bf16 matrix.
//   R2 restructure: attn split into two streaming kernels (k2v2 + attn_pv)
//   to kill the barrier-chain serialization seen in R1 counters (172us vs
//   59us byte-floor, VALUBusy 13%, occupancy 38%).

typedef unsigned short ushort_t;

using bf16x8 = __attribute__((ext_vector_type(8))) short;   // 8 bf16 (4 VGPRs)
using f32x4  = __attribute__((ext_vector_type(4))) float;   // MFMA acc

__device__ __forceinline__ float bf2f(unsigned short u) {
  union { unsigned int i; float f; } v;
  v.i = ((unsigned int)u) << 16;
  return v.f;
}
__device__ __forceinline__ unsigned short f2bf(float f) {
  __hip_bfloat16 h = __float2bfloat16(f);  // round-to-nearest-even
  return *reinterpret_cast<unsigned short*>(&h);
}

// async global->LDS, 16B per lane. LDS dest = wave-uniform base + lane*16.
__device__ __forceinline__ void load_lds16(const void* g, void* l) {
  __builtin_amdgcn_global_load_lds(
      (const __attribute__((address_space(1))) unsigned int*)g,
      (__attribute__((address_space(3))) unsigned int*)l,
      16, 0, 0);
}

// ---------------------------------------------------------------------------
// Kernel 0: fp32 -> bf16 cast, 4 elems/thread (x only).
// ---------------------------------------------------------------------------
__global__ __launch_bounds__(256)
void cast_f32_bf16(const float* __restrict__ src, ushort_t* __restrict__ dst,
                   int n4) {
  int i = blockIdx.x * blockDim.x + threadIdx.x;
  if (i < n4) {
    float4 v = ((const float4*)src)[i];
    ushort_t p[4] = {f2bf(v.x), f2bf(v.y), f2bf(v.z), f2bf(v.w)};
    *(uint2*)(dst + 4 * (size_t)i) = *(const uint2*)p;
  }
}

// Kernel 0b: all three W casts in one launch (saves 2 launch overheads).
// grid = 768 blocks; blocks [0,256) Wq, [256,512) Wk, [512,768) Wv.
__global__ __launch_bounds__(256)
void cast_w3(const float* __restrict__ Wq, const float* __restrict__ Wk,
             const float* __restrict__ Wv, ushort_t* __restrict__ dst) {
  int i = blockIdx.x * 256 + threadIdx.x;  // float4 index, 65536 per W
  int seg = i >> 16;
  int off = i & 65535;
  const float* src = (seg == 0) ? Wq : ((seg == 1) ? Wk : Wv);
  float4 v = ((const float4*)src)[off];
  ushort_t p[4] = {f2bf(v.x), f2bf(v.y), f2bf(v.z), f2bf(v.w)};
  *(uint2*)(dst + (size_t)seg * 262144u + 4 * (size_t)off) = *(const uint2*)p;
}

// ---------------------------------------------------------------------------
// Kernel 1: C[M=65536, N=512] = X[M,512] @ W[N,512]^T + bias, bf16 MFMA.
// grid = (N/128, M/128, 3); block = 256 (4 waves). BK=32, m97 2-barrier loop.
// R2: bijective XCD-chunk swizzle (nwg=6144, 6144%8==0) so the 4 N-blocks of
// each M-tile run on ONE XCD -> A-tile (128KB) L2-resident across them.
// ---------------------------------------------------------------------------
__global__ __launch_bounds__(256)
void gemm_qkv(const ushort_t* __restrict__ X,
              const ushort_t* __restrict__ W0, const float* __restrict__ B0,
              const ushort_t* __restrict__ W1, const float* __restrict__ B1,
              const ushort_t* __restrict__ W2, const float* __restrict__ B2,
              ushort_t* __restrict__ Qo, ushort_t* __restrict__ Ko,
              ushort_t* __restrict__ Vo) {
  __shared__ __align__(16) short sA[128 * 32];  // [row][k] row-major, no pad
  __shared__ __align__(16) short sB[128 * 32];

  // hardware dispatch id -> logical tile id, XCD-chunked (6144/8 = 768/XCD)
  const int fid = blockIdx.x + 4 * blockIdx.y + 2048 * blockIdx.z;
  const int swz = (fid & 7) * 768 + (fid >> 3);
  const int bz  = swz >> 11;          // /2048 : which of {q,k,v}
  const int rem = swz & 2047;
  const int by  = rem >> 2;           // M-tile
  const int bx  = rem & 3;            // N-tile

  const ushort_t* W;
  const float* Bi;
  ushort_t* O;
  if (bz == 0)      { W = W0; Bi = B0; O = Qo; }
  else if (bz == 1) { W = W1; Bi = B1; O = Ko; }
  else              { W = W2; Bi = B2; O = Vo; }

  const int tid  = threadIdx.x;
  const int lane = tid & 63;
  const int wid  = tid >> 6;
  const int m0 = by * 128;
  const int n0 = bx * 128;
  const int wave_m = (wid & 1) * 64;
  const int wave_n = (wid >> 1) * 64;
  const int quad = lane >> 4;
  const int l15  = lane & 15;

  f32x4 acc[4][4];
#pragma unroll
  for (int i = 0; i < 4; ++i)
#pragma unroll
    for (int j = 0; j < 4; ++j) acc[i][j] = f32x4{0.f, 0.f, 0.f, 0.f};

  // staging segments: 512 segs of 16B per tile; wave w covers [w*128, +128)
  const int s0 = wid * 128 + lane;
  const int s1 = s0 + 64;
  short* ldsA0 = &sA[(wid * 128) * 8];
  short* ldsA1 = &sA[(wid * 128 + 64) * 8];
  short* ldsB0 = &sB[(wid * 128) * 8];
  short* ldsB1 = &sB[(wid * 128 + 64) * 8];

  for (int kt = 0; kt < 512; kt += 32) {
    const ushort_t* ga0 = X + ((size_t)(m0 + (s0 >> 2)) << 9) + kt + (s0 & 3) * 8;
    const ushort_t* ga1 = X + ((size_t)(m0 + (s1 >> 2)) << 9) + kt + (s1 & 3) * 8;
    const ushort_t* gb0 = W + ((size_t)(n0 + (s0 >> 2)) << 9) + kt + (s0 & 3) * 8;
    const ushort_t* gb1 = W + ((size_t)(n0 + (s1 >> 2)) << 9) + kt + (s1 & 3) * 8;
    load_lds16(ga0, ldsA0);
    load_lds16(ga1, ldsA1);
    load_lds16(gb0, ldsB0);
    load_lds16(gb1, ldsB1);
    __syncthreads();  // drains vmcnt(0) -> LDS tiles valid

    bf16x8 af[4], bfr[4];
#pragma unroll
    for (int i = 0; i < 4; ++i)
      af[i] = *(const bf16x8*)&sA[(wave_m + i * 16 + l15) * 32 + quad * 8];
#pragma unroll
    for (int j = 0; j < 4; ++j)
      bfr[j] = *(const bf16x8*)&sB[(wave_n + j * 16 + l15) * 32 + quad * 8];
#pragma unroll
    for (int i = 0; i < 4; ++i)
#pragma unroll
      for (int j = 0; j < 4; ++j)
        acc[i][j] = __builtin_amdgcn_mfma_f32_16x16x32_bf16(af[i], bfr[j],
                                                            acc[i][j], 0, 0, 0);
    __syncthreads();  // all waves done reading before next stage overwrites
  }

  // epilogue: C/D layout col=lane&15, row=(lane>>4)*4+reg  [verified m89/m91]
#pragma unroll
  for (int j = 0; j < 4; ++j) {
    const int gn = n0 + wave_n + j * 16 + l15;
    const float bv = Bi[gn];
#pragma unroll
    for (int i = 0; i < 4; ++i) {
      const int gmBase = m0 + wave_m + i * 16 + quad * 4;
      f32x4 c = acc[i][j];
#pragma unroll
      for (int rg = 0; rg < 4; ++rg) {
        O[((size_t)(gmBase + rg) << 9) + gn] = f2bf(c[rg] + bv);
      }
    }
  }
}

// ---------------------------------------------------------------------------
// Kernel 2a (R2): k2/v2 factor contraction ONLY — pure streaming.
// grid = (64 a, 32 b); block = 256 (thread = (h, c): h=t>>2, c-chunk of 64 lr).
// k2g/v2g layout: [b][a][h][r] fp32 (contiguous 2KB per (b,a)).
// f[a] staged in LDS as 4 c-sub-arrays padded to 520 floats -> the 4 c-group
// broadcast reads per wave-instr hit disjoint bank sets (8c apart).
// ---------------------------------------------------------------------------
__global__ __launch_bounds__(256)
void k2v2_kernel(const ushort_t* __restrict__ K, const ushort_t* __restrict__ V,
                 const float* __restrict__ F,
                 float* __restrict__ k2g, float* __restrict__ v2g) {
  const int a = blockIdx.x;  // 0..63
  const int b = blockIdx.y;  // 0..31
  const int t = threadIdx.x;

  __shared__ float fs[4 * 520];  // 8.1 KB

  // stage f[a]: thread t loads f[a][lr=t][0..7]
  {
    const float* Fp = F + (size_t)a * 2048 + (size_t)t * 8;
    float4 f0 = *(const float4*)Fp;
    float4 f1 = *(const float4*)(Fp + 4);
    float* d = &fs[(t >> 6) * 520 + (t & 63) * 8];
    *(float4*)d = f0;
    *(float4*)(d + 4) = f1;
  }
  __syncthreads();

  const int h = t >> 2;
  const int c = t & 3;
  const size_t sliceoff = ((size_t)(b * 2048 + a * 32) << 9);
  const ushort_t* Kp = K + sliceoff + (size_t)h * 256 + c * 64;
  const ushort_t* Vp = V + sliceoff + (size_t)h * 256 + c * 64;

  // each thread's 128B of K (one line) and 128B of V: back-to-back loads
  uint4 kr[8], vr[8];
#pragma unroll
  for (int u = 0; u < 8; ++u) kr[u] = *(const uint4*)(Kp + u * 8);
#pragma unroll
  for (int u = 0; u < 8; ++u) vr[u] = *(const uint4*)(Vp + u * 8);

  const float* fb = &fs[c * 520];
  float accK[8], accV[8];
#pragma unroll
  for (int r = 0; r < 8; ++r) { accK[r] = 0.f; accV[r] = 0.f; }

#pragma unroll
  for (int u = 0; u < 8; ++u) {
    const unsigned short* ks = (const unsigned short*)&kr[u];
    const unsigned short* vs = (const unsigned short*)&vr[u];
#pragma unroll
    for (int j = 0; j < 8; ++j) {
      const float kv = bf2f(ks[j]);
      const float vv = bf2f(vs[j]);
      float fr[8];
      *(float4*)&fr[0] = *(const float4*)(fb + (u * 8 + j) * 8);
      *(float4*)&fr[4] = *(const float4*)(fb + (u * 8 + j) * 8 + 4);
#pragma unroll
      for (int r = 0; r < 8; ++r) {
        accK[r] += kv * fr[r];
        accV[r] += vv * fr[r];
      }
    }
  }
  // reduce across the 4 chunk-lanes (t^1, t^2 within same wave)
#pragma unroll
  for (int r = 0; r < 8; ++r) {
    accK[r] += __shfl_xor(accK[r], 1);
    accK[r] += __shfl_xor(accK[r], 2);
    accV[r] += __shfl_xor(accV[r], 1);
    accV[r] += __shfl_xor(accV[r], 2);
  }
  if (c == 0) {
    float* kd = k2g + (((size_t)b * 64 + a) * 64 + h) * 8;
    float* vd = v2g + (((size_t)b * 64 + a) * 64 + h) * 8;
    *(float4*)kd       = float4{accK[0], accK[1], accK[2], accK[3]};
    *(float4*)(kd + 4) = float4{accK[4], accK[5], accK[6], accK[7]};
    *(float4*)vd       = float4{accV[0], accV[1], accV[2], accV[3]};
    *(float4*)(vd + 4) = float4{accV[4], accV[5], accV[6], accV[7]};
  }
}

// ---------------------------------------------------------------------------
// Kernel 2b (R2): scores + softmax + PV + coalesced store.
// grid = (64 a, 32 b); block = 256 (thread = lr for scores phase).
// k2/v2 come from the 8MB global staging (L2-resident), transposed into LDS.
// ---------------------------------------------------------------------------
__global__ __launch_bounds__(256)
void attn_pv(const ushort_t* __restrict__ Q, const float* __restrict__ k2g,
             const float* __restrict__ v2g, float* __restrict__ Out) {
  const int a = blockIdx.x;  // 0..63
  const int b = blockIdx.y;  // 0..31
  const int t = threadIdx.x; // 0..255

  __shared__ float k2[64][8];    // [h][r]   2 KB (phase-2a reads broadcast)
  __shared__ float v2T[8][64];   // [r][h]   2 KB (phase-2b reads float4 on h)
  __shared__ float pl[256][8];   // [lr][r]  8 KB softmax probs

  // stage k2 (t<64) and v2 transposed (64<=t<128) from global
  {
    const size_t base = ((size_t)b * 64 + a) * 512;
    if (t < 64) {
      float4 x0 = *(const float4*)(k2g + base + t * 8);
      float4 x1 = *(const float4*)(k2g + base + t * 8 + 4);
      *(float4*)&k2[t][0] = x0;
      *(float4*)&k2[t][4] = x1;
    } else if (t < 128) {
      const int h = t - 64;
      float4 v0 = *(const float4*)(v2g + base + h * 8);
      float4 v1 = *(const float4*)(v2g + base + h * 8 + 4);
      v2T[0][h] = v0.x; v2T[1][h] = v0.y; v2T[2][h] = v0.z; v2T[3][h] = v0.w;
      v2T[4][h] = v1.x; v2T[5][h] = v1.y; v2T[6][h] = v1.z; v2T[7][h] = v1.w;
    }
  }
  __syncthreads();

  // ---- scores + softmax: thread t = lr --------------------------------
  {
    const int lr = t;
    float s[8];
#pragma unroll
    for (int r = 0; r < 8; ++r) s[r] = 0.f;

    const ushort_t* Qp = Q + (((size_t)(b * 2048 + a * 32)) << 9) + lr;
#pragma unroll 16
    for (int h = 0; h < 64; ++h) {
      const float qv = bf2f(Qp[(size_t)h * 256]);   // column read, 128B/wave
      float4 ka = *(const float4*)&k2[h][0];        // broadcast
      float4 kb = *(const float4*)&k2[h][4];
      s[0] += qv * ka.x; s[1] += qv * ka.y; s[2] += qv * ka.z; s[3] += qv * ka.w;
      s[4] += qv * kb.x; s[5] += qv * kb.y; s[6] += qv * kb.z; s[7] += qv * kb.w;
    }

    // scale by 1/sqrt(64), softmax over r (8)
    float mx = -1e30f;
#pragma unroll
    for (int r = 0; r < 8; ++r) { s[r] *= 0.125f; mx = fmaxf(mx, s[r]); }
    float sum = 0.f;
#pragma unroll
    for (int r = 0; r < 8; ++r) { s[r] = __expf(s[r] - mx); sum += s[r]; }
    const float inv = 1.0f / sum;
    *(float4*)&pl[lr][0] = float4{s[0] * inv, s[1] * inv, s[2] * inv, s[3] * inv};
    *(float4*)&pl[lr][4] = float4{s[4] * inv, s[5] * inv, s[6] * inv, s[7] * inv};
  }
  __syncthreads();

  // ---- coalesced PV + store -------------------------------------------
  // thread t owns out cols [g*64 + h0, +4) -> block writes 4KB contiguous per
  // iteration (16B/lane, full lines). out[row][g*64+h] = sum_r p[row*8+g][r]*v2[h][r]
  {
    float* Ob = Out + (((size_t)(b * 2048 + a * 32)) << 9);
    const int g  = (t >> 4) & 7;
    const int h0 = (t & 15) * 4;
#pragma unroll
    for (int iter = 0; iter < 16; ++iter) {
      const int row = (t >> 7) + iter * 2;
      const int lr = row * 8 + g;
      float p[8];
      *(float4*)&p[0] = *(const float4*)&pl[lr][0];   // broadcast within 16 lanes
      *(float4*)&p[4] = *(const float4*)&pl[lr][4];
      float4 o = float4{0.f, 0.f, 0.f, 0.f};
#pragma unroll
      for (int r = 0; r < 8; ++r) {
        float4 vt = *(const float4*)&v2T[r][h0];      // 2-way bank alias = free
        o.x += p[r] * vt.x; o.y += p[r] * vt.y;
        o.z += p[r] * vt.z; o.w += p[r] * vt.w;
      }
      *(float4*)(Ob + (size_t)row * 512 + g * 64 + h0) = o;
    }
  }
}

// ---------------------------------------------------------------------------
extern "C" void kernel_launch(void* const* d_in, const int* in_sizes, int n_in,
                              void* d_out, int out_size, void* d_ws,
                              size_t ws_size, hipStream_t stream) {
  const float* x  = (const float*)d_in[0];
  const float* Wq = (const float*)d_in[1];
  const float* bq = (const float*)d_in[2];
  const float* Wk = (const float*)d_in[3];
  const float* bk = (const float*)d_in[4];
  const float* Wv = (const float*)d_in[5];
  const float* bv = (const float*)d_in[6];
  const float* f  = (const float*)d_in[7];
  float* out = (float*)d_out;

  // ws layout (bf16 shorts):
  //   xb:  65536*512            = 33,554,432   (67 MB)  -- dead after gemm;
  //        reused as k2g/v2g (2 x 4 MB fp32) by k2v2/attn_pv.
  //   wb:  3 * 512*512          =    786,432   (1.5 MB)
  //   Qb/Kb/Vb: 3 * 33,554,432               (201 MB)
  ushort_t* xb = (ushort_t*)d_ws;
  ushort_t* wb = xb + 33554432u;
  ushort_t* Qb = wb + 786432u;
  ushort_t* Kb = Qb + 33554432u;
  ushort_t* Vb = Kb + 33554432u;
  float* k2g = (float*)d_ws;            // aliases xb (safe: gemm done)
  float* v2g = k2g + 1048576u;          // +4 MB

  cast_f32_bf16<<<33554432 / 4 / 256, 256, 0, stream>>>(x, xb, 33554432 / 4);
  cast_w3<<<768, 256, 0, stream>>>(Wq, Wk, Wv, wb);

  dim3 g1(4, 512, 3);  // N-blocks, M-blocks, {q,k,v}
  gemm_qkv<<<g1, 256, 0, stream>>>(xb, wb, bq, wb + 262144u, bk,
                                   wb + 524288u, bv, Qb, Kb, Vb);

  dim3 g2(64, 32);  // (a, b)
  k2v2_kernel<<<g2, 256, 0, stream>>>(Kb, Vb, f, k2g, v2g);
  attn_pv<<<g2, 256, 0, stream>>>(Qb, k2g, v2g, out);
}

// Round 3
// 454.001 us; speedup vs baseline: 1.3133x; 1.0347x over previous
//
#include <hip/hip_runtime.h>
#include <hip/hip_bf16.h>
#include <stdint.h>

// Problem constants
//   x:[32,2048,512] fp32  W*:[512,512] fp32  b*:[512] fp32  factor:[1,64,256,8] fp32
//   Output fp32 [32,2048,512].
//   Internally: cast x,W to bf16; q/k/v proj via bf16 MFMA; Q/K/V staged bf16.
//   per (b,a): slice = rows [b*2048+a*32, +32) x 512 of Q/K/V
//     slice IS a contiguous row-major [64 h][256 lr] bf16 matrix.
//   R3: gemm BK=64 (half the barrier drains) + LDS XOR swizzle chunk^=(row&7)
//   on both staging-source and ds_read (kills the 1.26e7 bank conflicts).

typedef unsigned short ushort_t;

using bf16x8 = __attribute__((ext_vector_type(8))) short;   // 8 bf16 (4 VGPRs)
using f32x4  = __attribute__((ext_vector_type(4))) float;   // MFMA acc

__device__ __forceinline__ float bf2f(unsigned short u) {
  union { unsigned int i; float f; } v;
  v.i = ((unsigned int)u) << 16;
  return v.f;
}
__device__ __forceinline__ unsigned short f2bf(float f) {
  __hip_bfloat16 h = __float2bfloat16(f);  // round-to-nearest-even
  return *reinterpret_cast<unsigned short*>(&h);
}

// async global->LDS, 16B per lane. LDS dest = wave-uniform base + lane*16.
__device__ __forceinline__ void load_lds16(const void* g, void* l) {
  __builtin_amdgcn_global_load_lds(
      (const __attribute__((address_space(1))) unsigned int*)g,
      (__attribute__((address_space(3))) unsigned int*)l,
      16, 0, 0);
}

// ---------------------------------------------------------------------------
// Kernel 0: fp32 -> bf16 cast, 4 elems/thread (x only).
// ---------------------------------------------------------------------------
__global__ __launch_bounds__(256)
void cast_f32_bf16(const float* __restrict__ src, ushort_t* __restrict__ dst,
                   int n4) {
  int i = blockIdx.x * blockDim.x + threadIdx.x;
  if (i < n4) {
    float4 v = ((const float4*)src)[i];
    ushort_t p[4] = {f2bf(v.x), f2bf(v.y), f2bf(v.z), f2bf(v.w)};
    *(uint2*)(dst + 4 * (size_t)i) = *(const uint2*)p;
  }
}

// Kernel 0b: all three W casts in one launch.
__global__ __launch_bounds__(256)
void cast_w3(const float* __restrict__ Wq, const float* __restrict__ Wk,
             const float* __restrict__ Wv, ushort_t* __restrict__ dst) {
  int i = blockIdx.x * 256 + threadIdx.x;  // float4 index, 65536 per W
  int seg = i >> 16;
  int off = i & 65535;
  const float* src = (seg == 0) ? Wq : ((seg == 1) ? Wk : Wv);
  float4 v = ((const float4*)src)[off];
  ushort_t p[4] = {f2bf(v.x), f2bf(v.y), f2bf(v.z), f2bf(v.w)};
  *(uint2*)(dst + (size_t)seg * 262144u + 4 * (size_t)off) = *(const uint2*)p;
}

// ---------------------------------------------------------------------------
// Kernel 1 (R3): C[M=65536, N=512] = X[M,512] @ W[N,512]^T + bias, bf16 MFMA.
// grid = (4, 512, 3); block = 256 (4 waves). 128x128 tile, BK=64, 2-barrier
// loop (8 K-iterations). LDS tiles [128 rows][64 cols] bf16 (128B rows).
// Swizzle: 16B-chunk within a row, chunk' = chunk ^ (row&7)  (involution).
//   - staging: linear LDS dest (global_load_lds requirement), SOURCE address
//     pre-swizzled:  src col-chunk = (c&7) ^ ((c>>3)&7).
//   - ds_read: addr = row*64 + ((ks*4+quad) ^ (row&7))*8  -> bank = 4*ch',
//     16 l15-rows cover all 8 chunk positions twice -> 2-way = free.
// XCD-chunk swizzle kept (6144 % 8 == 0, bijective).
// ---------------------------------------------------------------------------
__global__ __launch_bounds__(256)
void gemm_qkv(const ushort_t* __restrict__ X,
              const ushort_t* __restrict__ W0, const float* __restrict__ B0,
              const ushort_t* __restrict__ W1, const float* __restrict__ B1,
              const ushort_t* __restrict__ W2, const float* __restrict__ B2,
              ushort_t* __restrict__ Qo, ushort_t* __restrict__ Ko,
              ushort_t* __restrict__ Vo) {
  __shared__ __align__(16) short sA[128 * 64];  // 16 KB
  __shared__ __align__(16) short sB[128 * 64];  // 16 KB

  // hardware dispatch id -> logical tile id, XCD-chunked (6144/8 = 768/XCD)
  const int fid = blockIdx.x + 4 * blockIdx.y + 2048 * blockIdx.z;
  const int swz = (fid & 7) * 768 + (fid >> 3);
  const int bz  = swz >> 11;          // /2048 : which of {q,k,v}
  const int rem = swz & 2047;
  const int by  = rem >> 2;           // M-tile
  const int bx  = rem & 3;            // N-tile

  const ushort_t* W;
  const float* Bi;
  ushort_t* O;
  if (bz == 0)      { W = W0; Bi = B0; O = Qo; }
  else if (bz == 1) { W = W1; Bi = B1; O = Ko; }
  else              { W = W2; Bi = B2; O = Vo; }

  const int tid  = threadIdx.x;
  const int lane = tid & 63;
  const int wid  = tid >> 6;
  const int m0 = by * 128;
  const int n0 = bx * 128;
  const int wave_m = (wid & 1) * 64;
  const int wave_n = (wid >> 1) * 64;
  const int quad = lane >> 4;
  const int l15  = lane & 15;

  f32x4 acc[4][4];
#pragma unroll
  for (int i = 0; i < 4; ++i)
#pragma unroll
    for (int j = 0; j < 4; ++j) acc[i][j] = f32x4{0.f, 0.f, 0.f, 0.f};

  // staging: 1024 chunks of 16B per [128][64] tile; thread covers chunk
  // c = q*256 + wid*64 + lane for q=0..3 (LDS base uniform per wave ✓).
  // precompute per-q source row / swizzled col-chunk
  int srow[4], scol[4];
#pragma unroll
  for (int q = 0; q < 4; ++q) {
    const int c = q * 256 + wid * 64 + lane;
    srow[q] = c >> 3;
    scol[q] = ((c & 7) ^ ((c >> 3) & 7)) * 8;   // pre-swizzled source col (elems)
  }

  for (int kt = 0; kt < 512; kt += 64) {
#pragma unroll
    for (int q = 0; q < 4; ++q) {
      const ushort_t* ga = X + ((size_t)(m0 + srow[q]) << 9) + kt + scol[q];
      const ushort_t* gb = W + ((size_t)(n0 + srow[q]) << 9) + kt + scol[q];
      short* la = &sA[(q * 256 + wid * 64) * 8];
      short* lb = &sB[(q * 256 + wid * 64) * 8];
      load_lds16(ga, la);
      load_lds16(gb, lb);
    }
    __syncthreads();  // drains vmcnt(0) -> LDS tiles valid

#pragma unroll
    for (int ks = 0; ks < 2; ++ks) {
      bf16x8 af[4], bfr[4];
#pragma unroll
      for (int i = 0; i < 4; ++i) {
        const int row = wave_m + i * 16 + l15;
        af[i] = *(const bf16x8*)&sA[row * 64 + ((ks * 4 + quad) ^ (row & 7)) * 8];
      }
#pragma unroll
      for (int j = 0; j < 4; ++j) {
        const int row = wave_n + j * 16 + l15;
        bfr[j] = *(const bf16x8*)&sB[row * 64 + ((ks * 4 + quad) ^ (row & 7)) * 8];
      }
#pragma unroll
      for (int i = 0; i < 4; ++i)
#pragma unroll
        for (int j = 0; j < 4; ++j)
          acc[i][j] = __builtin_amdgcn_mfma_f32_16x16x32_bf16(af[i], bfr[j],
                                                              acc[i][j], 0, 0, 0);
    }
    __syncthreads();  // all waves done reading before next stage overwrites
  }

  // epilogue: C/D layout col=lane&15, row=(lane>>4)*4+reg  [verified m89/m91]
#pragma unroll
  for (int j = 0; j < 4; ++j) {
    const int gn = n0 + wave_n + j * 16 + l15;
    const float bv = Bi[gn];
#pragma unroll
    for (int i = 0; i < 4; ++i) {
      const int gmBase = m0 + wave_m + i * 16 + quad * 4;
      f32x4 c = acc[i][j];
#pragma unroll
      for (int rg = 0; rg < 4; ++rg) {
        O[((size_t)(gmBase + rg) << 9) + gn] = f2bf(c[rg] + bv);
      }
    }
  }
}

// ---------------------------------------------------------------------------
// Kernel 2a: k2/v2 factor contraction ONLY — pure streaming.
// grid = (64 a, 32 b); block = 256 (thread = (h, c): h=t>>2, c-chunk of 64 lr).
// ---------------------------------------------------------------------------
__global__ __launch_bounds__(256)
void k2v2_kernel(const ushort_t* __restrict__ K, const ushort_t* __restrict__ V,
                 const float* __restrict__ F,
                 float* __restrict__ k2g, float* __restrict__ v2g) {
  const int a = blockIdx.x;  // 0..63
  const int b = blockIdx.y;  // 0..31
  const int t = threadIdx.x;

  __shared__ float fs[4 * 520];  // 8.1 KB

  // stage f[a]: thread t loads f[a][lr=t][0..7]
  {
    const float* Fp = F + (size_t)a * 2048 + (size_t)t * 8;
    float4 f0 = *(const float4*)Fp;
    float4 f1 = *(const float4*)(Fp + 4);
    float* d = &fs[(t >> 6) * 520 + (t & 63) * 8];
    *(float4*)d = f0;
    *(float4*)(d + 4) = f1;
  }
  __syncthreads();

  const int h = t >> 2;
  const int c = t & 3;
  const size_t sliceoff = ((size_t)(b * 2048 + a * 32) << 9);
  const ushort_t* Kp = K + sliceoff + (size_t)h * 256 + c * 64;
  const ushort_t* Vp = V + sliceoff + (size_t)h * 256 + c * 64;

  // each thread's 128B of K (one line) and 128B of V: back-to-back loads
  uint4 kr[8], vr[8];
#pragma unroll
  for (int u = 0; u < 8; ++u) kr[u] = *(const uint4*)(Kp + u * 8);
#pragma unroll
  for (int u = 0; u < 8; ++u) vr[u] = *(const uint4*)(Vp + u * 8);

  const float* fb = &fs[c * 520];
  float accK[8], accV[8];
#pragma unroll
  for (int r = 0; r < 8; ++r) { accK[r] = 0.f; accV[r] = 0.f; }

#pragma unroll
  for (int u = 0; u < 8; ++u) {
    const unsigned short* ks = (const unsigned short*)&kr[u];
    const unsigned short* vs = (const unsigned short*)&vr[u];
#pragma unroll
    for (int j = 0; j < 8; ++j) {
      const float kv = bf2f(ks[j]);
      const float vv = bf2f(vs[j]);
      float fr[8];
      *(float4*)&fr[0] = *(const float4*)(fb + (u * 8 + j) * 8);
      *(float4*)&fr[4] = *(const float4*)(fb + (u * 8 + j) * 8 + 4);
#pragma unroll
      for (int r = 0; r < 8; ++r) {
        accK[r] += kv * fr[r];
        accV[r] += vv * fr[r];
      }
    }
  }
  // reduce across the 4 chunk-lanes (t^1, t^2 within same wave)
#pragma unroll
  for (int r = 0; r < 8; ++r) {
    accK[r] += __shfl_xor(accK[r], 1);
    accK[r] += __shfl_xor(accK[r], 2);
    accV[r] += __shfl_xor(accV[r], 1);
    accV[r] += __shfl_xor(accV[r], 2);
  }
  if (c == 0) {
    float* kd = k2g + (((size_t)b * 64 + a) * 64 + h) * 8;
    float* vd = v2g + (((size_t)b * 64 + a) * 64 + h) * 8;
    *(float4*)kd       = float4{accK[0], accK[1], accK[2], accK[3]};
    *(float4*)(kd + 4) = float4{accK[4], accK[5], accK[6], accK[7]};
    *(float4*)vd       = float4{accV[0], accV[1], accV[2], accV[3]};
    *(float4*)(vd + 4) = float4{accV[4], accV[5], accV[6], accV[7]};
  }
}

// ---------------------------------------------------------------------------
// Kernel 2b: scores + softmax + PV + coalesced store.
// grid = (64 a, 32 b); block = 256 (thread = lr for scores phase).
// ---------------------------------------------------------------------------
__global__ __launch_bounds__(256)
void attn_pv(const ushort_t* __restrict__ Q, const float* __restrict__ k2g,
             const float* __restrict__ v2g, float* __restrict__ Out) {
  const int a = blockIdx.x;  // 0..63
  const int b = blockIdx.y;  // 0..31
  const int t = threadIdx.x; // 0..255

  __shared__ float k2[64][8];    // [h][r]   2 KB
  __shared__ float v2T[8][64];   // [r][h]   2 KB
  __shared__ float pl[256][8];   // [lr][r]  8 KB softmax probs

  // stage k2 (t<64) and v2 transposed (64<=t<128) from global
  {
    const size_t base = ((size_t)b * 64 + a) * 512;
    if (t < 64) {
      float4 x0 = *(const float4*)(k2g + base + t * 8);
      float4 x1 = *(const float4*)(k2g + base + t * 8 + 4);
      *(float4*)&k2[t][0] = x0;
      *(float4*)&k2[t][4] = x1;
    } else if (t < 128) {
      const int h = t - 64;
      float4 v0 = *(const float4*)(v2g + base + h * 8);
      float4 v1 = *(const float4*)(v2g + base + h * 8 + 4);
      v2T[0][h] = v0.x; v2T[1][h] = v0.y; v2T[2][h] = v0.z; v2T[3][h] = v0.w;
      v2T[4][h] = v1.x; v2T[5][h] = v1.y; v2T[6][h] = v1.z; v2T[7][h] = v1.w;
    }
  }
  __syncthreads();

  // ---- scores + softmax: thread t = lr --------------------------------
  {
    const int lr = t;
    float s[8];
#pragma unroll
    for (int r = 0; r < 8; ++r) s[r] = 0.f;

    const ushort_t* Qp = Q + (((size_t)(b * 2048 + a * 32)) << 9) + lr;
#pragma unroll 16
    for (int h = 0; h < 64; ++h) {
      const float qv = bf2f(Qp[(size_t)h * 256]);   // column read, 128B/wave
      float4 ka = *(const float4*)&k2[h][0];        // broadcast
      float4 kb = *(const float4*)&k2[h][4];
      s[0] += qv * ka.x; s[1] += qv * ka.y; s[2] += qv * ka.z; s[3] += qv * ka.w;
      s[4] += qv * kb.x; s[5] += qv * kb.y; s[6] += qv * kb.z; s[7] += qv * kb.w;
    }

    // scale by 1/sqrt(64), softmax over r (8)
    float mx = -1e30f;
#pragma unroll
    for (int r = 0; r < 8; ++r) { s[r] *= 0.125f; mx = fmaxf(mx, s[r]); }
    float sum = 0.f;
#pragma unroll
    for (int r = 0; r < 8; ++r) { s[r] = __expf(s[r] - mx); sum += s[r]; }
    const float inv = 1.0f / sum;
    *(float4*)&pl[lr][0] = float4{s[0] * inv, s[1] * inv, s[2] * inv, s[3] * inv};
    *(float4*)&pl[lr][4] = float4{s[4] * inv, s[5] * inv, s[6] * inv, s[7] * inv};
  }
  __syncthreads();

  // ---- coalesced PV + store -------------------------------------------
  {
    float* Ob = Out + (((size_t)(b * 2048 + a * 32)) << 9);
    const int g  = (t >> 4) & 7;
    const int h0 = (t & 15) * 4;
#pragma unroll
    for (int iter = 0; iter < 16; ++iter) {
      const int row = (t >> 7) + iter * 2;
      const int lr = row * 8 + g;
      float p[8];
      *(float4*)&p[0] = *(const float4*)&pl[lr][0];   // broadcast within 16 lanes
      *(float4*)&p[4] = *(const float4*)&pl[lr][4];
      float4 o = float4{0.f, 0.f, 0.f, 0.f};
#pragma unroll
      for (int r = 0; r < 8; ++r) {
        float4 vt = *(const float4*)&v2T[r][h0];      // 2-way bank alias = free
        o.x += p[r] * vt.x; o.y += p[r] * vt.y;
        o.z += p[r] * vt.z; o.w += p[r] * vt.w;
      }
      *(float4*)(Ob + (size_t)row * 512 + g * 64 + h0) = o;
    }
  }
}

// ---------------------------------------------------------------------------
extern "C" void kernel_launch(void* const* d_in, const int* in_sizes, int n_in,
                              void* d_out, int out_size, void* d_ws,
                              size_t ws_size, hipStream_t stream) {
  const float* x  = (const float*)d_in[0];
  const float* Wq = (const float*)d_in[1];
  const float* bq = (const float*)d_in[2];
  const float* Wk = (const float*)d_in[3];
  const float* bk = (const float*)d_in[4];
  const float* Wv = (const float*)d_in[5];
  const float* bv = (const float*)d_in[6];
  const float* f  = (const float*)d_in[7];
  float* out = (float*)d_out;

  // ws layout (bf16 shorts):
  //   xb:  65536*512            = 33,554,432   (67 MB)  -- dead after gemm;
  //        reused as k2g/v2g (2 x 4 MB fp32) by k2v2/attn_pv.
  //   wb:  3 * 512*512          =    786,432   (1.5 MB)
  //   Qb/Kb/Vb: 3 * 33,554,432               (201 MB)
  ushort_t* xb = (ushort_t*)d_ws;
  ushort_t* wb = xb + 33554432u;
  ushort_t* Qb = wb + 786432u;
  ushort_t* Kb = Qb + 33554432u;
  ushort_t* Vb = Kb + 33554432u;
  float* k2g = (float*)d_ws;            // aliases xb (safe: gemm done)
  float* v2g = k2g + 1048576u;          // +4 MB

  cast_f32_bf16<<<33554432 / 4 / 256, 256, 0, stream>>>(x, xb, 33554432 / 4);
  cast_w3<<<768, 256, 0, stream>>>(Wq, Wk, Wv, wb);

  dim3 g1(4, 512, 3);  // N-blocks, M-blocks, {q,k,v}
  gemm_qkv<<<g1, 256, 0, stream>>>(xb, wb, bq, wb + 262144u, bk,
                                   wb + 524288u, bv, Qb, Kb, Vb);

  dim3 g2(64, 32);  // (a, b)
  k2v2_kernel<<<g2, 256, 0, stream>>>(Kb, Vb, f, k2g, v2g);
  attn_pv<<<g2, 256, 0, stream>>>(Qb, k2g, v2g, out);
}

// Round 4
// 401.146 us; speedup vs baseline: 1.4864x; 1.1318x over previous
//
#include <hip/hip_runtime.h>
#include <hip/hip_bf16.h>
#include <stdint.h>

// Problem constants
//   x:[32,2048,512] fp32  W*:[512,512] fp32  b*:[512] fp32  factor:[1,64,256,8] fp32
//   Output fp32 [32,2048,512].
//   R4 restructure: K/V are only consumed via the rank-8 factor contraction,
//   which commutes through the linear projection:
//     k2[b,a,h,r] = sum_d X[b, a*32+h>>1, d] * Wk2[a, h&1, r, d] + bk2[a,h&1,r]
//     Wk2[a,p,r,d] = sum_lr Wk[p*256+lr, d] * f[a,lr,r]  (2MB precompute)
//   -> K/V full GEMMs + K/V materialization + k2v2 streaming kernel all
//   deleted. Only the Q GEMM (1/3 of old gemm_qkv) + tiny batched GEMM remain.

typedef unsigned short ushort_t;

using bf16x8 = __attribute__((ext_vector_type(8))) short;   // 8 bf16 (4 VGPRs)
using f32x4  = __attribute__((ext_vector_type(4))) float;   // MFMA acc

__device__ __forceinline__ float bf2f(unsigned short u) {
  union { unsigned int i; float f; } v;
  v.i = ((unsigned int)u) << 16;
  return v.f;
}
__device__ __forceinline__ unsigned short f2bf(float f) {
  __hip_bfloat16 h = __float2bfloat16(f);  // round-to-nearest-even
  return *reinterpret_cast<unsigned short*>(&h);
}

// async global->LDS, 16B per lane. LDS dest = wave-uniform base + lane*16.
__device__ __forceinline__ void load_lds16(const void* g, void* l) {
  __builtin_amdgcn_global_load_lds(
      (const __attribute__((address_space(1))) unsigned int*)g,
      (__attribute__((address_space(3))) unsigned int*)l,
      16, 0, 0);
}

// ---------------------------------------------------------------------------
// Kernel 0: fp32 -> bf16 cast, 4 elems/thread (x and Wq).
// ---------------------------------------------------------------------------
__global__ __launch_bounds__(256)
void cast_f32_bf16(const float* __restrict__ src, ushort_t* __restrict__ dst,
                   int n4) {
  int i = blockIdx.x * blockDim.x + threadIdx.x;
  if (i < n4) {
    float4 v = ((const float4*)src)[i];
    ushort_t p[4] = {f2bf(v.x), f2bf(v.y), f2bf(v.z), f2bf(v.w)};
    *(uint2*)(dst + 4 * (size_t)i) = *(const uint2*)p;
  }
}

// ---------------------------------------------------------------------------
// Kernel 1 (R4): Wk2/Wv2 precompute.
// grid = (64 a, 2 kv); block = 256.
//   Wo[a][p][r][d] = sum_lr W[p*256+lr][d] * f[a][lr][r]   (bf16 out)
//   bo[a][p*8+r]   = sum_lr B[p*256+lr]    * f[a][lr][r]   (fp32 out)
// W column-block reads are 256B/wave contiguous; W is 1MB -> L3-resident
// after the first block streams it.
// ---------------------------------------------------------------------------
__global__ __launch_bounds__(256)
void wkv2_pre(const float* __restrict__ Wk, const float* __restrict__ bk,
              const float* __restrict__ Wv, const float* __restrict__ bv,
              const float* __restrict__ F,
              ushort_t* __restrict__ Wk2b, ushort_t* __restrict__ Wv2b,
              float* __restrict__ bk2g, float* __restrict__ bv2g) {
  const int a  = blockIdx.x;
  const int kv = blockIdx.y;
  const float* W = kv ? Wv : Wk;
  const float* B = kv ? bv : bk;
  ushort_t* Wo = kv ? Wv2b : Wk2b;
  float* bo = kv ? bv2g : bk2g;
  const int t = threadIdx.x;

  __shared__ float fs[256][8];  // f[a][lr][r], 8 KB
  {
    const float* Fp = F + (size_t)a * 2048 + (size_t)t * 8;
    *(float4*)&fs[t][0] = *(const float4*)Fp;
    *(float4*)&fs[t][4] = *(const float4*)(Fp + 4);
  }
  __syncthreads();

  for (int dblk = 0; dblk < 2; ++dblk) {
    const int d = dblk * 256 + t;
    float acc[2][8];
#pragma unroll
    for (int p = 0; p < 2; ++p)
#pragma unroll
      for (int r = 0; r < 8; ++r) acc[p][r] = 0.f;

    for (int lr = 0; lr < 256; ++lr) {
      const float w0 = W[(size_t)lr * 512 + d];          // p=0
      const float w1 = W[(size_t)(256 + lr) * 512 + d];  // p=1
      float4 fa = *(const float4*)&fs[lr][0];            // broadcast
      float4 fb = *(const float4*)&fs[lr][4];
      acc[0][0] += w0 * fa.x; acc[0][1] += w0 * fa.y;
      acc[0][2] += w0 * fa.z; acc[0][3] += w0 * fa.w;
      acc[0][4] += w0 * fb.x; acc[0][5] += w0 * fb.y;
      acc[0][6] += w0 * fb.z; acc[0][7] += w0 * fb.w;
      acc[1][0] += w1 * fa.x; acc[1][1] += w1 * fa.y;
      acc[1][2] += w1 * fa.z; acc[1][3] += w1 * fa.w;
      acc[1][4] += w1 * fb.x; acc[1][5] += w1 * fb.y;
      acc[1][6] += w1 * fb.z; acc[1][7] += w1 * fb.w;
    }
#pragma unroll
    for (int p = 0; p < 2; ++p)
#pragma unroll
      for (int r = 0; r < 8; ++r)
        Wo[((size_t)(a * 2 + p) * 8 + r) * 512 + d] = f2bf(acc[p][r]);
  }

  if (t < 16) {  // bias contraction: p = t>>3, r = t&7
    const int p = t >> 3, r = t & 7;
    float s = 0.f;
    for (int lr = 0; lr < 256; ++lr) s += B[p * 256 + lr] * fs[lr][r];
    bo[a * 16 + t] = s;
  }
}

// ---------------------------------------------------------------------------
// Kernel 2 (R4): Q GEMM only. C[M=65536,512] = X @ Wq^T + bq, bf16 MFMA.
// grid = (4, 512); block = 256 (4 waves). 128x128 tile, BK=64, 2-barrier loop,
// chunk^(row&7) LDS swizzle (R3, conflict-free), XCD-chunk swizzle (2048%8==0).
// ---------------------------------------------------------------------------
__global__ __launch_bounds__(256)
void gemm_q(const ushort_t* __restrict__ X, const ushort_t* __restrict__ W,
            const float* __restrict__ Bi, ushort_t* __restrict__ O) {
  __shared__ __align__(16) short sA[128 * 64];  // 16 KB
  __shared__ __align__(16) short sB[128 * 64];  // 16 KB

  // dispatch id -> logical tile id, XCD-chunked (2048/8 = 256 per XCD)
  const int fid = blockIdx.x + 4 * blockIdx.y;
  const int swz = (fid & 7) * 256 + (fid >> 3);
  const int by  = swz >> 2;           // M-tile
  const int bx  = swz & 3;            // N-tile

  const int tid  = threadIdx.x;
  const int lane = tid & 63;
  const int wid  = tid >> 6;
  const int m0 = by * 128;
  const int n0 = bx * 128;
  const int wave_m = (wid & 1) * 64;
  const int wave_n = (wid >> 1) * 64;
  const int quad = lane >> 4;
  const int l15  = lane & 15;

  f32x4 acc[4][4];
#pragma unroll
  for (int i = 0; i < 4; ++i)
#pragma unroll
    for (int j = 0; j < 4; ++j) acc[i][j] = f32x4{0.f, 0.f, 0.f, 0.f};

  int srow[4], scol[4];
#pragma unroll
  for (int q = 0; q < 4; ++q) {
    const int c = q * 256 + wid * 64 + lane;
    srow[q] = c >> 3;
    scol[q] = ((c & 7) ^ ((c >> 3) & 7)) * 8;   // pre-swizzled source col
  }

  for (int kt = 0; kt < 512; kt += 64) {
#pragma unroll
    for (int q = 0; q < 4; ++q) {
      const ushort_t* ga = X + ((size_t)(m0 + srow[q]) << 9) + kt + scol[q];
      const ushort_t* gb = W + ((size_t)(n0 + srow[q]) << 9) + kt + scol[q];
      load_lds16(ga, &sA[(q * 256 + wid * 64) * 8]);
      load_lds16(gb, &sB[(q * 256 + wid * 64) * 8]);
    }
    __syncthreads();

#pragma unroll
    for (int ks = 0; ks < 2; ++ks) {
      bf16x8 af[4], bfr[4];
#pragma unroll
      for (int i = 0; i < 4; ++i) {
        const int row = wave_m + i * 16 + l15;
        af[i] = *(const bf16x8*)&sA[row * 64 + ((ks * 4 + quad) ^ (row & 7)) * 8];
      }
#pragma unroll
      for (int j = 0; j < 4; ++j) {
        const int row = wave_n + j * 16 + l15;
        bfr[j] = *(const bf16x8*)&sB[row * 64 + ((ks * 4 + quad) ^ (row & 7)) * 8];
      }
#pragma unroll
      for (int i = 0; i < 4; ++i)
#pragma unroll
        for (int j = 0; j < 4; ++j)
          acc[i][j] = __builtin_amdgcn_mfma_f32_16x16x32_bf16(af[i], bfr[j],
                                                              acc[i][j], 0, 0, 0);
    }
    __syncthreads();
  }

  // epilogue: C/D layout col=lane&15, row=(lane>>4)*4+reg
#pragma unroll
  for (int j = 0; j < 4; ++j) {
    const int gn = n0 + wave_n + j * 16 + l15;
    const float bv = Bi[gn];
#pragma unroll
    for (int i = 0; i < 4; ++i) {
      const int gmBase = m0 + wave_m + i * 16 + quad * 4;
      f32x4 c = acc[i][j];
#pragma unroll
      for (int rg = 0; rg < 4; ++rg) {
        O[((size_t)(gmBase + rg) << 9) + gn] = f2bf(c[rg] + bv);
      }
    }
  }
}

// ---------------------------------------------------------------------------
// Kernel 3 (R4): batched thin GEMM  k2/v2[b,a,h,r].
// grid = (64 a, 32 b); block = 256 (4 waves: kv = wid>>1, mf = wid&1).
// Per block: M=32 token rows (l = b*2048+a*32+lh), N=16 (p*8+r), K=512.
//   sX[32][512], sW[32][512] (K rows 0-15, V rows 16-31), chunk^(row&7)
//   swizzle on both staging-source and ds_read (same involution as gemm_q).
// 16 MFMA per wave; purely staging-bound (reads X once = 67 MB total).
// ---------------------------------------------------------------------------
__global__ __launch_bounds__(256)
void k2v2_gemm(const ushort_t* __restrict__ X,
               const ushort_t* __restrict__ Wk2b,
               const ushort_t* __restrict__ Wv2b,
               const float* __restrict__ bk2g, const float* __restrict__ bv2g,
               float* __restrict__ k2g, float* __restrict__ v2g) {
  const int a = blockIdx.x;  // 0..63
  const int b = blockIdx.y;  // 0..31
  __shared__ __align__(16) short sX[32 * 512];  // 32 KB
  __shared__ __align__(16) short sW[32 * 512];  // 32 KB

  const int t = threadIdx.x;
  const int lane = t & 63;
  const int wid  = t >> 6;

  // stage: 2048 16B-chunks each for X and W (8 per thread)
#pragma unroll
  for (int q = 0; q < 8; ++q) {
    const int c = q * 256 + wid * 64 + lane;
    const int row = c >> 6;                     // 0..31
    const int sch = (c & 63) ^ (row & 7);       // pre-swizzled source chunk
    const ushort_t* gx =
        X + ((size_t)(b * 2048 + a * 32 + row) << 9) + sch * 8;
    const ushort_t* gw =
        (row < 16 ? Wk2b + (size_t)(a * 16 + row) * 512
                  : Wv2b + (size_t)(a * 16 + row - 16) * 512) + sch * 8;
    load_lds16(gx, &sX[(q * 256 + wid * 64) * 8]);
    load_lds16(gw, &sW[(q * 256 + wid * 64) * 8]);
  }
  __syncthreads();

  const int kv = wid >> 1;      // 0: k2, 1: v2
  const int mf = wid & 1;       // M-frag (lh 0-15 / 16-31)
  const int quad = lane >> 4;
  const int l15  = lane & 15;

  f32x4 acc = f32x4{0.f, 0.f, 0.f, 0.f};
  const int arow = mf * 16 + l15;
  const int brow = kv * 16 + l15;
#pragma unroll
  for (int ks = 0; ks < 16; ++ks) {
    bf16x8 af =
        *(const bf16x8*)&sX[arow * 512 + (((ks * 4 + quad) ^ (arow & 7))) * 8];
    bf16x8 bf_ =
        *(const bf16x8*)&sW[brow * 512 + (((ks * 4 + quad) ^ (brow & 7))) * 8];
    acc = __builtin_amdgcn_mfma_f32_16x16x32_bf16(af, bf_, acc, 0, 0, 0);
  }

  // epilogue: col = l15 = p*8+r, row = quad*4+rg = lh (local to mf half)
  const float* bb = kv ? bv2g : bk2g;
  float* og = kv ? v2g : k2g;
  const float bias = bb[a * 16 + l15];
  const size_t obase = ((size_t)(b * 64 + a)) * 512;  // 64 h x 8 r
#pragma unroll
  for (int rg = 0; rg < 4; ++rg) {
    const int lh = mf * 16 + quad * 4 + rg;
    const int h = 2 * lh + (l15 >> 3);
    const int r = l15 & 7;
    og[obase + h * 8 + r] = acc[rg] + bias;
  }
}

// ---------------------------------------------------------------------------
// Kernel 4: scores + softmax + PV + coalesced store (unchanged from R3).
// grid = (64 a, 32 b); block = 256 (thread = lr for scores phase).
// ---------------------------------------------------------------------------
__global__ __launch_bounds__(256)
void attn_pv(const ushort_t* __restrict__ Q, const float* __restrict__ k2g,
             const float* __restrict__ v2g, float* __restrict__ Out) {
  const int a = blockIdx.x;  // 0..63
  const int b = blockIdx.y;  // 0..31
  const int t = threadIdx.x; // 0..255

  __shared__ float k2[64][8];    // [h][r]   2 KB
  __shared__ float v2T[8][64];   // [r][h]   2 KB
  __shared__ float pl[256][8];   // [lr][r]  8 KB softmax probs

  // stage k2 (t<64) and v2 transposed (64<=t<128) from global
  {
    const size_t base = ((size_t)b * 64 + a) * 512;
    if (t < 64) {
      float4 x0 = *(const float4*)(k2g + base + t * 8);
      float4 x1 = *(const float4*)(k2g + base + t * 8 + 4);
      *(float4*)&k2[t][0] = x0;
      *(float4*)&k2[t][4] = x1;
    } else if (t < 128) {
      const int h = t - 64;
      float4 v0 = *(const float4*)(v2g + base + h * 8);
      float4 v1 = *(const float4*)(v2g + base + h * 8 + 4);
      v2T[0][h] = v0.x; v2T[1][h] = v0.y; v2T[2][h] = v0.z; v2T[3][h] = v0.w;
      v2T[4][h] = v1.x; v2T[5][h] = v1.y; v2T[6][h] = v1.z; v2T[7][h] = v1.w;
    }
  }
  __syncthreads();

  // ---- scores + softmax: thread t = lr --------------------------------
  {
    const int lr = t;
    float s[8];
#pragma unroll
    for (int r = 0; r < 8; ++r) s[r] = 0.f;

    const ushort_t* Qp = Q + (((size_t)(b * 2048 + a * 32)) << 9) + lr;
#pragma unroll 16
    for (int h = 0; h < 64; ++h) {
      const float qv = bf2f(Qp[(size_t)h * 256]);   // column read, 128B/wave
      float4 ka = *(const float4*)&k2[h][0];        // broadcast
      float4 kb = *(const float4*)&k2[h][4];
      s[0] += qv * ka.x; s[1] += qv * ka.y; s[2] += qv * ka.z; s[3] += qv * ka.w;
      s[4] += qv * kb.x; s[5] += qv * kb.y; s[6] += qv * kb.z; s[7] += qv * kb.w;
    }

    // scale by 1/sqrt(64), softmax over r (8)
    float mx = -1e30f;
#pragma unroll
    for (int r = 0; r < 8; ++r) { s[r] *= 0.125f; mx = fmaxf(mx, s[r]); }
    float sum = 0.f;
#pragma unroll
    for (int r = 0; r < 8; ++r) { s[r] = __expf(s[r] - mx); sum += s[r]; }
    const float inv = 1.0f / sum;
    *(float4*)&pl[lr][0] = float4{s[0] * inv, s[1] * inv, s[2] * inv, s[3] * inv};
    *(float4*)&pl[lr][4] = float4{s[4] * inv, s[5] * inv, s[6] * inv, s[7] * inv};
  }
  __syncthreads();

  // ---- coalesced PV + store -------------------------------------------
  {
    float* Ob = Out + (((size_t)(b * 2048 + a * 32)) << 9);
    const int g  = (t >> 4) & 7;
    const int h0 = (t & 15) * 4;
#pragma unroll
    for (int iter = 0; iter < 16; ++iter) {
      const int row = (t >> 7) + iter * 2;
      const int lr = row * 8 + g;
      float p[8];
      *(float4*)&p[0] = *(const float4*)&pl[lr][0];   // broadcast within 16 lanes
      *(float4*)&p[4] = *(const float4*)&pl[lr][4];
      float4 o = float4{0.f, 0.f, 0.f, 0.f};
#pragma unroll
      for (int r = 0; r < 8; ++r) {
        float4 vt = *(const float4*)&v2T[r][h0];      // 2-way bank alias = free
        o.x += p[r] * vt.x; o.y += p[r] * vt.y;
        o.z += p[r] * vt.z; o.w += p[r] * vt.w;
      }
      *(float4*)(Ob + (size_t)row * 512 + g * 64 + h0) = o;
    }
  }
}

// ---------------------------------------------------------------------------
extern "C" void kernel_launch(void* const* d_in, const int* in_sizes, int n_in,
                              void* d_out, int out_size, void* d_ws,
                              size_t ws_size, hipStream_t stream) {
  const float* x  = (const float*)d_in[0];
  const float* Wq = (const float*)d_in[1];
  const float* bq = (const float*)d_in[2];
  const float* Wk = (const float*)d_in[3];
  const float* bk = (const float*)d_in[4];
  const float* Wv = (const float*)d_in[5];
  const float* bv = (const float*)d_in[6];
  const float* f  = (const float*)d_in[7];
  float* out = (float*)d_out;

  // ws layout (shorts unless noted):
  //   xb:    33,554,432  (67 MB)    x bf16
  //   wqb:      262,144  (0.5 MB)   Wq bf16
  //   Qb:    33,554,432  (67 MB)    Q bf16
  //   Wk2b:     524,288  (1 MB)     [64a][2p][8r][512d] bf16
  //   Wv2b:     524,288  (1 MB)
  //   then fp32: k2g 1,048,576 f (4 MB), v2g 1,048,576 f,
  //              bk2g 1024 f, bv2g 1024 f
  ushort_t* xb   = (ushort_t*)d_ws;
  ushort_t* wqb  = xb + 33554432u;
  ushort_t* Qb   = wqb + 262144u;
  ushort_t* Wk2b = Qb + 33554432u;
  ushort_t* Wv2b = Wk2b + 524288u;
  float* k2g  = (float*)(Wv2b + 524288u);
  float* v2g  = k2g + 1048576u;
  float* bk2g = v2g + 1048576u;
  float* bv2g = bk2g + 1024u;

  cast_f32_bf16<<<32768, 256, 0, stream>>>(x, xb, 8388608);
  cast_f32_bf16<<<256, 256, 0, stream>>>(Wq, wqb, 65536);

  dim3 gp(64, 2);  // (a, kv)
  wkv2_pre<<<gp, 256, 0, stream>>>(Wk, bk, Wv, bv, f, Wk2b, Wv2b, bk2g, bv2g);

  dim3 g1(4, 512);  // N-blocks, M-blocks
  gemm_q<<<g1, 256, 0, stream>>>(xb, wqb, bq, Qb);

  dim3 g2(64, 32);  // (a, b)
  k2v2_gemm<<<g2, 256, 0, stream>>>(xb, Wk2b, Wv2b, bk2g, bv2g, k2g, v2g);
  attn_pv<<<g2, 256, 0, stream>>>(Qb, k2g, v2g, out);
}

// Round 5
// 325.981 us; speedup vs baseline: 1.8291x; 1.2306x over previous
//
#include <hip/hip_runtime.h>
#include <hip/hip_bf16.h>
#include <stdint.h>

// Problem constants
//   x:[32,2048,512] fp32  W*:[512,512] fp32  b*:[512] fp32  factor:[1,64,256,8] fp32
//   Output fp32 [32,2048,512].
//   R5 restructure: BOTH K/V and Q projections are algebraically folded.
//     k2[b,a,h,r] = sum_d X[b,a*32+(h>>1),d]*Wk2[a,h&1,r,d] + bk2   (R4 trick)
//     scores*8    = sum_{p,d} Wq2[lr][p*512+d]*g[ba][p][r][d] + bq-term
//       g[p][r][d] = sum_lh X[a*32+lh,d]*k2full[2lh+p][r]
//       sk[p][r]   = sum_lh k2full[2lh+p][r]   (bias contraction)
//   -> no Q GEMM, no Q buffer, no x cast. X fp32 read exactly once (xfold).
//   Kernels: cast_wq2, wkv2_pre (256 blocks now), xfold, scores_pv (fused
//   skinny GEMM + softmax + PV + store; S never materialized).

typedef unsigned short ushort_t;

using bf16x8 = __attribute__((ext_vector_type(8))) short;   // 8 bf16 (4 VGPRs)
using f32x4  = __attribute__((ext_vector_type(4))) float;   // MFMA acc

__device__ __forceinline__ float bf2f(unsigned short u) {
  union { unsigned int i; float f; } v;
  v.i = ((unsigned int)u) << 16;
  return v.f;
}
__device__ __forceinline__ unsigned short f2bf(float f) {
  __hip_bfloat16 h = __float2bfloat16(f);  // round-to-nearest-even
  return *reinterpret_cast<unsigned short*>(&h);
}

// async global->LDS, 16B per lane. LDS dest = wave-uniform base + lane*16.
__device__ __forceinline__ void load_lds16(const void* g, void* l) {
  __builtin_amdgcn_global_load_lds(
      (const __attribute__((address_space(1))) unsigned int*)g,
      (__attribute__((address_space(3))) unsigned int*)l,
      16, 0, 0);
}

// ---------------------------------------------------------------------------
// Kernel 0: Wq -> Wq2b[lr][p*512+d] bf16 (cast + reshuffle). 256 blocks.
// Wq row index = p*256+lr; dest row lr, col-block p. Coalesced both sides.
// ---------------------------------------------------------------------------
__global__ __launch_bounds__(256)
void cast_wq2(const float* __restrict__ Wq, ushort_t* __restrict__ Wq2b) {
  const int i = blockIdx.x * 256 + threadIdx.x;  // float4 id, 65536 total
  float4 v = ((const float4*)Wq)[i];
  const int row = i >> 7;      // Wq row (128 float4 per row)
  const int c4  = i & 127;
  const int lr = row & 255;
  const int p  = row >> 8;
  ushort_t pk[4] = {f2bf(v.x), f2bf(v.y), f2bf(v.z), f2bf(v.w)};
  *(uint2*)(Wq2b + (size_t)lr * 1024 + p * 512 + c4 * 4) = *(const uint2*)pk;
}

// ---------------------------------------------------------------------------
// Kernel 1: Wk2/Wv2 precompute. grid = (64 a, 2 kv, 2 dblk) = 256 blocks
// (R5: dblk moved to grid.z -- R4's 128-block version was latency-bound).
//   Wo[a*16 + p*8 + r][d] = sum_lr W[p*256+lr][d] * f[a][lr][r]   (bf16)
//   bo[a*16 + p*8 + r]    = sum_lr B[p*256+lr]    * f[a][lr][r]   (fp32)
// ---------------------------------------------------------------------------
__global__ __launch_bounds__(256)
void wkv2_pre(const float* __restrict__ Wk, const float* __restrict__ bk,
              const float* __restrict__ Wv, const float* __restrict__ bv,
              const float* __restrict__ F,
              ushort_t* __restrict__ Wk2b, ushort_t* __restrict__ Wv2b,
              float* __restrict__ bk2g, float* __restrict__ bv2g) {
  const int a    = blockIdx.x;
  const int kv   = blockIdx.y;
  const int dblk = blockIdx.z;
  const float* W = kv ? Wv : Wk;
  const float* B = kv ? bv : bk;
  ushort_t* Wo = kv ? Wv2b : Wk2b;
  float* bo = kv ? bv2g : bk2g;
  const int t = threadIdx.x;

  __shared__ float fs[256][8];  // f[a][lr][r], 8 KB
  {
    const float* Fp = F + (size_t)a * 2048 + (size_t)t * 8;
    *(float4*)&fs[t][0] = *(const float4*)Fp;
    *(float4*)&fs[t][4] = *(const float4*)(Fp + 4);
  }
  __syncthreads();

  const int d = dblk * 256 + t;
  float acc[2][8];
#pragma unroll
  for (int p = 0; p < 2; ++p)
#pragma unroll
    for (int r = 0; r < 8; ++r) acc[p][r] = 0.f;

#pragma unroll 4
  for (int lr = 0; lr < 256; ++lr) {
    const float w0 = W[(size_t)lr * 512 + d];
    const float w1 = W[(size_t)(256 + lr) * 512 + d];
    float4 fa = *(const float4*)&fs[lr][0];
    float4 fb = *(const float4*)&fs[lr][4];
    acc[0][0] += w0 * fa.x; acc[0][1] += w0 * fa.y;
    acc[0][2] += w0 * fa.z; acc[0][3] += w0 * fa.w;
    acc[0][4] += w0 * fb.x; acc[0][5] += w0 * fb.y;
    acc[0][6] += w0 * fb.z; acc[0][7] += w0 * fb.w;
    acc[1][0] += w1 * fa.x; acc[1][1] += w1 * fa.y;
    acc[1][2] += w1 * fa.z; acc[1][3] += w1 * fa.w;
    acc[1][4] += w1 * fb.x; acc[1][5] += w1 * fb.y;
    acc[1][6] += w1 * fb.z; acc[1][7] += w1 * fb.w;
  }
#pragma unroll
  for (int p = 0; p < 2; ++p)
#pragma unroll
    for (int r = 0; r < 8; ++r)
      Wo[(size_t)(a * 16 + p * 8 + r) * 512 + d] = f2bf(acc[p][r]);

  if (dblk == 0 && t < 16) {  // bias contraction
    const int p = t >> 3, r = t & 7;
    float s = 0.f;
    for (int lr = 0; lr < 256; ++lr) s += B[p * 256 + lr] * fs[lr][r];
    bo[a * 16 + t] = s;
  }
}

// ---------------------------------------------------------------------------
// Kernel 2 (R5): xfold. grid = (64 a, 32 b); block = 256 (4 waves).
// Reads the 32x512 fp32 X slice ONCE; produces:
//   v2g[ba][64h][8r] fp32, skg[ba][16] fp32, G[ba*8+r][p*512+d] bf16.
// Phase A: stage X fp32->bf16 (chunk^(lh&7) swizzle), stage Wk2/Wv2 rows via
//          global_load_lds (pre-swizzled source, linear dest -- rule #21).
// Phase B: k2/v2 MFMA (identical to R4's verified k2v2_gemm); k2full -> LDS.
// Phase C: sk sums; g on VALU (thread = (p, 4-d-block); 1024 FMA, k2s reads
//          wave-uniform broadcast, X reads conflict-free via swizzle).
// ---------------------------------------------------------------------------
__global__ __launch_bounds__(256)
void xfold(const float* __restrict__ X,
           const ushort_t* __restrict__ Wk2b, const ushort_t* __restrict__ Wv2b,
           const float* __restrict__ bk2g, const float* __restrict__ bv2g,
           ushort_t* __restrict__ Gb, float* __restrict__ v2g,
           float* __restrict__ skg) {
  const int a = blockIdx.x;  // 0..63
  const int b = blockIdx.y;  // 0..31
  const int t = threadIdx.x;
  const int lane = t & 63, wid = t >> 6;
  const int quad = lane >> 4, l15 = lane & 15;
  const int ba = b * 64 + a;

  __shared__ __align__(16) short sX[32 * 512];  // 32 KB
  __shared__ __align__(16) short sW[32 * 512];  // 32 KB (K rows 0-15, V 16-31)
  __shared__ float k2s[64][8];                  // 2 KB

  // ---- Phase A: staging ----
#pragma unroll
  for (int q = 0; q < 8; ++q) {
    const int c = q * 256 + wid * 64 + lane;
    const int row = c >> 6;
    const int sch = (c & 63) ^ (row & 7);
    const ushort_t* gw =
        (row < 16 ? Wk2b + (size_t)(a * 16 + row) * 512
                  : Wv2b + (size_t)(a * 16 + row - 16) * 512) + sch * 8;
    load_lds16(gw, &sW[(q * 256 + wid * 64) * 8]);
  }
#pragma unroll
  for (int q = 0; q < 8; ++q) {
    const int c = q * 256 + t;
    const int lh = c >> 6, ch = c & 63;
    const float* gx = X + ((size_t)(b * 2048 + a * 32 + lh) << 9) + ch * 8;
    float4 x0 = *(const float4*)gx;
    float4 x1 = *(const float4*)(gx + 4);
    ushort_t pk[8] = {f2bf(x0.x), f2bf(x0.y), f2bf(x0.z), f2bf(x0.w),
                      f2bf(x1.x), f2bf(x1.y), f2bf(x1.z), f2bf(x1.w)};
    *(bf16x8*)&sX[lh * 512 + ((ch ^ (lh & 7)) << 3)] = *(const bf16x8*)pk;
  }
  __syncthreads();

  // ---- Phase B: k2/v2 MFMA (R4-verified) ----
  const int kv = wid >> 1;  // 0: k2, 1: v2
  const int mf = wid & 1;   // M-half
  f32x4 acc = f32x4{0.f, 0.f, 0.f, 0.f};
  const int arow = mf * 16 + l15;
  const int brow = kv * 16 + l15;
#pragma unroll
  for (int ks = 0; ks < 16; ++ks) {
    bf16x8 af  = *(const bf16x8*)&sX[arow * 512 + ((ks * 4 + quad) ^ (arow & 7)) * 8];
    bf16x8 bf_ = *(const bf16x8*)&sW[brow * 512 + ((ks * 4 + quad) ^ (brow & 7)) * 8];
    acc = __builtin_amdgcn_mfma_f32_16x16x32_bf16(af, bf_, acc, 0, 0, 0);
  }
  const float bias = (kv ? bv2g : bk2g)[a * 16 + l15];
  if (kv == 0) {
#pragma unroll
    for (int rg = 0; rg < 4; ++rg) {
      const int lh = mf * 16 + quad * 4 + rg;
      k2s[2 * lh + (l15 >> 3)][l15 & 7] = acc[rg] + bias;  // k2full incl. bias
    }
  } else {
    const size_t obase = (size_t)ba * 512;
#pragma unroll
    for (int rg = 0; rg < 4; ++rg) {
      const int lh = mf * 16 + quad * 4 + rg;
      const int h = 2 * lh + (l15 >> 3);
      v2g[obase + h * 8 + (l15 & 7)] = acc[rg] + bias;
    }
  }
  __syncthreads();

  // ---- Phase C: sk + g ----
  if (t < 16) {
    const int p = t >> 3, r = t & 7;
    float s = 0.f;
#pragma unroll
    for (int lh = 0; lh < 32; ++lh) s += k2s[2 * lh + p][r];
    skg[ba * 16 + t] = s;
  }
  {
    const int p  = t >> 7;          // wave-uniform
    const int d0 = (t & 127) * 4;
    float g[4][8];
#pragma unroll
    for (int dd = 0; dd < 4; ++dd)
#pragma unroll
      for (int r = 0; r < 8; ++r) g[dd][r] = 0.f;

#pragma unroll
    for (int lh = 0; lh < 32; ++lh) {
      float kr[8];
      *(float4*)&kr[0] = *(const float4*)&k2s[2 * lh + p][0];  // broadcast
      *(float4*)&kr[4] = *(const float4*)&k2s[2 * lh + p][4];
      const int ch = d0 >> 3;
      uint2 xr = *(const uint2*)&sX[lh * 512 + ((ch ^ (lh & 7)) << 3) + (d0 & 7)];
      const ushort_t* xs = (const ushort_t*)&xr;
      float xv[4] = {bf2f(xs[0]), bf2f(xs[1]), bf2f(xs[2]), bf2f(xs[3])};
#pragma unroll
      for (int dd = 0; dd < 4; ++dd)
#pragma unroll
        for (int r = 0; r < 8; ++r) g[dd][r] += xv[dd] * kr[r];
    }
#pragma unroll
    for (int r = 0; r < 8; ++r) {
      ushort_t pk[4] = {f2bf(g[0][r]), f2bf(g[1][r]), f2bf(g[2][r]),
                        f2bf(g[3][r])};
      *(uint2*)(Gb + (((size_t)(ba * 8 + r)) << 10) + p * 512 + d0) =
          *(const uint2*)pk;
    }
  }
}

// ---------------------------------------------------------------------------
// Kernel 3 (R5): scores_pv. grid = 1024 ba-pairs; block = 256 (4 waves).
// GEMM: S[256 lr][16 = 2ba x 8r] = Wq2b(256x1024) . G(pair rows)^T, BK=64,
// 2-barrier loop, chunk^(row&7) swizzle (R3-verified conflict-free).
// Then +bias (bq (.) sk), *0.125, softmax over r, PV with v2, coalesced store.
// Wq2b (512 KB) is read by every block -> L2-resident; S stays in LDS.
// ---------------------------------------------------------------------------
__global__ __launch_bounds__(256)
void scores_pv(const ushort_t* __restrict__ Wq2b, const ushort_t* __restrict__ Gb,
               const float* __restrict__ bq, const float* __restrict__ skg,
               const float* __restrict__ v2g, float* __restrict__ Out) {
  const int P = blockIdx.x;  // ba-pair: rows 16P..16P+15 of G
  const int t = threadIdx.x;
  const int lane = t & 63, wid = t >> 6;
  const int quad = lane >> 4, l15 = lane & 15;

  __shared__ __align__(16) short sA[256 * 64];  // 32 KB  Wq2 K-tile
  __shared__ __align__(16) short sB[16 * 64];   // 2 KB   G K-tile
  __shared__ float sS[256 * 16];                // 16 KB  scores -> probs
  __shared__ float v2T[2][8][64];               // 4 KB
  __shared__ float sks[32];

  // stage v2T + sks (consumed only after the GEMM barriers)
  if (t < 128) {
    const int pa = t >> 6, h = t & 63;
    const float* vp = v2g + (size_t)(2 * P + pa) * 512 + h * 8;
    float4 v0 = *(const float4*)vp;
    float4 v1 = *(const float4*)(vp + 4);
    v2T[pa][0][h] = v0.x; v2T[pa][1][h] = v0.y;
    v2T[pa][2][h] = v0.z; v2T[pa][3][h] = v0.w;
    v2T[pa][4][h] = v1.x; v2T[pa][5][h] = v1.y;
    v2T[pa][6][h] = v1.z; v2T[pa][7][h] = v1.w;
  }
  if (t < 32) sks[t] = skg[P * 32 + t];

  f32x4 acc[4];
#pragma unroll
  for (int i = 0; i < 4; ++i) acc[i] = f32x4{0.f, 0.f, 0.f, 0.f};

  const int wave_m = wid * 64;
  const int grow0 = P * 16;

  for (int kt = 0; kt < 1024; kt += 64) {
#pragma unroll
    for (int q = 0; q < 8; ++q) {
      const int c = q * 256 + wid * 64 + lane;
      const int row = c >> 3, ch = c & 7;
      load_lds16(Wq2b + (size_t)row * 1024 + kt + ((ch ^ (row & 7)) << 3),
                 &sA[(q * 256 + wid * 64) * 8]);
    }
    if (wid < 2) {
      const int c = wid * 64 + lane;
      const int row = c >> 3, ch = c & 7;
      load_lds16(Gb + (size_t)(grow0 + row) * 1024 + kt + ((ch ^ (row & 7)) << 3),
                 &sB[(wid * 64) * 8]);
    }
    __syncthreads();
#pragma unroll
    for (int ks = 0; ks < 2; ++ks) {
      bf16x8 bfrag =
          *(const bf16x8*)&sB[l15 * 64 + (((ks * 4 + quad) ^ (l15 & 7)) << 3)];
#pragma unroll
      for (int i = 0; i < 4; ++i) {
        const int row = wave_m + i * 16 + l15;
        bf16x8 afrag =
            *(const bf16x8*)&sA[row * 64 + (((ks * 4 + quad) ^ (row & 7)) << 3)];
        acc[i] = __builtin_amdgcn_mfma_f32_16x16x32_bf16(afrag, bfrag, acc[i],
                                                         0, 0, 0);
      }
    }
    __syncthreads();
  }

  // S -> LDS (C/D layout: col=l15, row=quad*4+rg)
#pragma unroll
  for (int i = 0; i < 4; ++i)
#pragma unroll
    for (int rg = 0; rg < 4; ++rg)
      sS[(wave_m + i * 16 + quad * 4 + rg) * 16 + l15] = acc[i][rg];
  __syncthreads();

  // bias + scale + softmax over r (thread = lr, both ba of the pair)
  {
    const int lr = t;
    const float bq0 = bq[lr];
    const float bq1 = bq[256 + lr];
#pragma unroll
    for (int pa = 0; pa < 2; ++pa) {
      float s[8];
      *(float4*)&s[0] = *(const float4*)&sS[lr * 16 + pa * 8];
      *(float4*)&s[4] = *(const float4*)&sS[lr * 16 + pa * 8 + 4];
      float mx = -1e30f;
#pragma unroll
      for (int r = 0; r < 8; ++r) {
        s[r] = (s[r] + bq0 * sks[pa * 16 + r] + bq1 * sks[pa * 16 + 8 + r]) *
               0.125f;
        mx = fmaxf(mx, s[r]);
      }
      float sum = 0.f;
#pragma unroll
      for (int r = 0; r < 8; ++r) { s[r] = __expf(s[r] - mx); sum += s[r]; }
      const float inv = 1.0f / sum;
      *(float4*)&sS[lr * 16 + pa * 8] =
          float4{s[0] * inv, s[1] * inv, s[2] * inv, s[3] * inv};
      *(float4*)&sS[lr * 16 + pa * 8 + 4] =
          float4{s[4] * inv, s[5] * inv, s[6] * inv, s[7] * inv};
    }
  }
  __syncthreads();

  // PV + coalesced store (4KB/block-instr, full lines)
  {
    const int b  = (2 * P) >> 6;
    const int a0 = (2 * P) & 63;
    const int g0 = (t >> 4) & 7;
    const int h0 = (t & 15) * 4;
#pragma unroll
    for (int pa = 0; pa < 2; ++pa) {
      float* Ob = Out + (((size_t)(b * 2048 + (a0 + pa) * 32)) << 9);
#pragma unroll
      for (int iter = 0; iter < 16; ++iter) {
        const int row = (t >> 7) + iter * 2;
        const int lr = row * 8 + g0;
        float p[8];
        *(float4*)&p[0] = *(const float4*)&sS[lr * 16 + pa * 8];
        *(float4*)&p[4] = *(const float4*)&sS[lr * 16 + pa * 8 + 4];
        float4 o = float4{0.f, 0.f, 0.f, 0.f};
#pragma unroll
        for (int r = 0; r < 8; ++r) {
          float4 vt = *(const float4*)&v2T[pa][r][h0];
          o.x += p[r] * vt.x; o.y += p[r] * vt.y;
          o.z += p[r] * vt.z; o.w += p[r] * vt.w;
        }
        *(float4*)(Ob + (size_t)row * 512 + g0 * 64 + h0) = o;
      }
    }
  }
}

// ---------------------------------------------------------------------------
extern "C" void kernel_launch(void* const* d_in, const int* in_sizes, int n_in,
                              void* d_out, int out_size, void* d_ws,
                              size_t ws_size, hipStream_t stream) {
  const float* x  = (const float*)d_in[0];
  const float* Wq = (const float*)d_in[1];
  const float* bq = (const float*)d_in[2];
  const float* Wk = (const float*)d_in[3];
  const float* bk = (const float*)d_in[4];
  const float* Wv = (const float*)d_in[5];
  const float* bv = (const float*)d_in[6];
  const float* f  = (const float*)d_in[7];
  float* out = (float*)d_out;

  // ws layout:
  //   Wq2b: 262,144 sh (512 KB)   [lr][p*512+d] bf16
  //   Wk2b: 524,288 sh (1 MB)     [a*16+p*8+r][d] bf16
  //   Wv2b: 524,288 sh (1 MB)
  //   Gb:   16,777,216 sh (32 MB) [ba*8+r][p*512+d] bf16
  //   v2g:  1,048,576 f (4 MB)    [ba][h][r] fp32
  //   bk2g/bv2g: 1024 f each; skg: 32,768 f  [ba][p*8+r]
  ushort_t* Wq2b = (ushort_t*)d_ws;
  ushort_t* Wk2b = Wq2b + 262144u;
  ushort_t* Wv2b = Wk2b + 524288u;
  ushort_t* Gb   = Wv2b + 524288u;
  float* v2g  = (float*)(Gb + 16777216u);
  float* bk2g = v2g + 1048576u;
  float* bv2g = bk2g + 1024u;
  float* skg  = bv2g + 1024u;

  cast_wq2<<<256, 256, 0, stream>>>(Wq, Wq2b);

  dim3 gp(64, 2, 2);  // (a, kv, dblk)
  wkv2_pre<<<gp, 256, 0, stream>>>(Wk, bk, Wv, bv, f, Wk2b, Wv2b, bk2g, bv2g);

  dim3 gx(64, 32);  // (a, b)
  xfold<<<gx, 256, 0, stream>>>(x, Wk2b, Wv2b, bk2g, bv2g, Gb, v2g, skg);

  scores_pv<<<1024, 256, 0, stream>>>(Wq2b, Gb, bq, skg, v2g, out);
}